// Round 1
// baseline (637.134 us; speedup 1.0000x reference)
//
#include <hip/hip_runtime.h>

#define D_  1024
#define B_  8
#define P_  4
#define LQk 1024
#define LKk 1024

typedef __attribute__((ext_vector_type(8))) short bf16x8;
typedef __attribute__((ext_vector_type(4))) float f32x4;
typedef __attribute__((ext_vector_type(8))) unsigned short ushort8v;

__device__ __forceinline__ unsigned short f2bf(float f) {
  unsigned int u = __float_as_uint(f);
  u += 0x7FFFu + ((u >> 16) & 1u);           // RNE
  return (unsigned short)(u >> 16);
}

__device__ __forceinline__ void gload_lds16(const void* g, void* l) {
  __builtin_amdgcn_global_load_lds(
      (const __attribute__((address_space(1))) unsigned int*)g,
      (__attribute__((address_space(3))) unsigned int*)l, 16, 0, 0);
}

// ---------------- fp32 -> bf16 convert (exact grid, 8 elems/thread) ----------------
__global__ __launch_bounds__(256) void convert_bf16_kernel(const float* __restrict__ in,
                                                           unsigned short* __restrict__ out) {
  long i = ((long)blockIdx.x * 256 + threadIdx.x) * 8;
  float4 v0 = *(const float4*)(in + i);
  float4 v1 = *(const float4*)(in + i + 4);
  ushort8v r;
  r[0] = f2bf(v0.x); r[1] = f2bf(v0.y); r[2] = f2bf(v0.z); r[3] = f2bf(v0.w);
  r[4] = f2bf(v1.x); r[5] = f2bf(v1.y); r[6] = f2bf(v1.z); r[7] = f2bf(v1.w);
  *(ushort8v*)(out + i) = r;
}

__global__ __launch_bounds__(256) void zero_kernel(float* __restrict__ p) {
  p[blockIdx.x * 256 + threadIdx.x] = 0.f;
}

// Qmean[b][d] = (1/LQ) sum_q Q[b,q,d] ; grid (4, 8, 16), atomics across q-chunks
__global__ __launch_bounds__(256) void qmean_kernel(const float* __restrict__ Q,
                                                    float* __restrict__ Qm) {
  int d = blockIdx.x * 256 + threadIdx.x;
  int b = blockIdx.y;
  int q0 = blockIdx.z * 64;
  const float* q = Q + ((long)b * LQk + q0) * D_ + d;
  float s = 0.f;
  #pragma unroll 8
  for (int i = 0; i < 64; ++i) s += q[(long)i * D_];
  atomicAdd(&Qm[b * D_ + d], s * (1.0f / 1024.0f));
}

// out[b][e] = act(X[b]·W[e] + bias[e]); one wave per output; grid 2048 x 256thr
template<int RELU>
__global__ __launch_bounds__(256) void matvec_kernel(const float* __restrict__ X,
                                                     const float* __restrict__ W,
                                                     const float* __restrict__ bias,
                                                     float* __restrict__ out) {
  int g = blockIdx.x * 4 + (threadIdx.x >> 6);
  int lane = threadIdx.x & 63;
  int b = g >> 10, e = g & 1023;
  const float* x = X + b * D_;
  const float* w = W + (long)e * D_;
  float s = 0.f;
  #pragma unroll
  for (int k = lane * 4; k < D_; k += 256) {
    float4 xv = *(const float4*)(x + k);
    float4 wv = *(const float4*)(w + k);
    s += xv.x * wv.x + xv.y * wv.y + xv.z * wv.z + xv.w * wv.w;
  }
  #pragma unroll
  for (int o = 32; o; o >>= 1) s += __shfl_xor(s, o, 64);
  if (lane == 0) {
    s += bias[e];
    if (RELU) s = fmaxf(s, 0.f);
    out[b * D_ + e] = s;
  }
}

// path logits -> softmax -> top-2 (strict >, ties to lower index = lax.top_k) -> renormalized weights
__global__ __launch_bounds__(256) void gate_kernel(const float* __restrict__ h,
                                                   const float* __restrict__ Wm2,
                                                   const float* __restrict__ bm2,
                                                   int* __restrict__ sel,
                                                   float* __restrict__ wsel) {
  __shared__ float lg[B_][P_];
  int lane = threadIdx.x & 63, wid = threadIdx.x >> 6;
  #pragma unroll
  for (int i = 0; i < 8; ++i) {
    int pair = wid * 8 + i;
    int b = pair >> 2, p = pair & 3;
    const float* x = h + b * D_;
    const float* w = Wm2 + p * D_;
    float s = 0.f;
    for (int k = lane; k < D_; k += 64) s += x[k] * w[k];
    #pragma unroll
    for (int o = 32; o; o >>= 1) s += __shfl_xor(s, o, 64);
    if (lane == 0) lg[b][p] = s + bm2[p];
  }
  __syncthreads();
  if (threadIdx.x < B_) {
    int b = threadIdx.x;
    float v0 = lg[b][0], v1 = lg[b][1], v2 = lg[b][2], v3 = lg[b][3];
    float m = fmaxf(fmaxf(v0, v1), fmaxf(v2, v3));
    float e[4];
    e[0] = __expf(v0 - m); e[1] = __expf(v1 - m);
    e[2] = __expf(v2 - m); e[3] = __expf(v3 - m);
    float sum = e[0] + e[1] + e[2] + e[3];
    int p0 = 0;
    for (int p = 1; p < 4; ++p) if (e[p] > e[p0]) p0 = p;
    int p1 = -1;
    for (int p = 0; p < 4; ++p) { if (p == p0) continue; if (p1 < 0 || e[p] > e[p1]) p1 = p; }
    float s0 = e[p0] / sum, s1 = e[p1] / sum;
    float dn = s0 + s1 + 1e-8f;
    sel[b * 2] = p0; sel[b * 2 + 1] = p1;
    wsel[b * 2] = s0 / dn; wsel[b * 2 + 1] = s1 / dn;
  }
}

// copy+convert selected src[p][b] slices to bf16; grid (512, 16)
__global__ __launch_bounds__(256) void select_convert_kernel(const float* __restrict__ src,
                                                             const int* __restrict__ sel,
                                                             unsigned short* __restrict__ out) {
  int z = blockIdx.y; int b = z >> 1; int p = sel[z];
  const float* s = src + ((long)p * B_ + b) * (1024L * 1024);
  unsigned short* o = out + (long)z * (1024L * 1024);
  long i = ((long)blockIdx.x * 256 + threadIdx.x) * 8;
  float4 v0 = *(const float4*)(s + i);
  float4 v1 = *(const float4*)(s + i + 4);
  ushort8v r;
  r[0] = f2bf(v0.x); r[1] = f2bf(v0.y); r[2] = f2bf(v0.z); r[3] = f2bf(v0.w);
  r[4] = f2bf(v1.x); r[5] = f2bf(v1.y); r[6] = f2bf(v1.z); r[7] = f2bf(v1.w);
  *(ushort8v*)(o + i) = r;
}

// row softmax over 1024 fp32 logits, fold 1/sqrt(D) and gate weight, emit bf16
__global__ __launch_bounds__(256) void softmax_kernel(const float* __restrict__ S,
                                                      unsigned short* __restrict__ P,
                                                      const float* __restrict__ wsel) {
  int z = blockIdx.y;
  int row = blockIdx.x * 4 + (threadIdx.x >> 6);
  int lane = threadIdx.x & 63;
  const float* s = S + ((long)z * LQk + row) * LKk;
  float4 v[4];
  #pragma unroll
  for (int i = 0; i < 4; ++i) v[i] = *(const float4*)(s + (lane + i * 64) * 4);
  float m = -1e30f;
  #pragma unroll
  for (int i = 0; i < 4; ++i)
    m = fmaxf(m, fmaxf(fmaxf(v[i].x, v[i].y), fmaxf(v[i].z, v[i].w)));
  #pragma unroll
  for (int o = 32; o; o >>= 1) m = fmaxf(m, __shfl_xor(m, o, 64));
  const float sc = 0.03125f;  // 1/sqrt(1024), exact
  float sum = 0.f;
  #pragma unroll
  for (int i = 0; i < 4; ++i) {
    v[i].x = __expf((v[i].x - m) * sc);
    v[i].y = __expf((v[i].y - m) * sc);
    v[i].z = __expf((v[i].z - m) * sc);
    v[i].w = __expf((v[i].w - m) * sc);
    sum += v[i].x + v[i].y + v[i].z + v[i].w;
  }
  #pragma unroll
  for (int o = 32; o; o >>= 1) sum += __shfl_xor(sum, o, 64);
  float wf = wsel[z] / sum;
  unsigned short* p = P + ((long)z * LQk + row) * LKk;
  #pragma unroll
  for (int i = 0; i < 4; ++i) {
    ushort4 r;
    r.x = f2bf(v[i].x * wf); r.y = f2bf(v[i].y * wf);
    r.z = f2bf(v[i].z * wf); r.w = f2bf(v[i].w * wf);
    *(ushort4*)(p + (lane + i * 64) * 4) = r;
  }
}

// ---------------- NT GEMM: C[M,N] = A[M,K]·B[N,K]^T (+bias) ----------------
// m97 structure: 128x128 tile, BK=32, 4 waves, 16x16x32 bf16 MFMA, global_load_lds w16.
// lda=ldb=ldc=1024 always. SEL_MODE: 0 idx=z, 1 A by sel[z], 2 B by sel[z], 3 A by z>>1.
// SPLITK2: K=2048 split over two 1M-elem segments (PV over both slots).
template<int BIAS_MODE, int OUT_BF16, int SEL_MODE, int SPLITK2>
__global__ __launch_bounds__(256) void gemm_nt(
    const unsigned short* __restrict__ A0, long sAz, long segA,
    const unsigned short* __restrict__ B0, long sBz, long segB,
    const float* __restrict__ bias0, long sBiasz,
    void* __restrict__ C0, long sCz,
    const int* __restrict__ sel, int K) {
  __shared__ unsigned short As[128 * 32];
  __shared__ unsigned short Bs[128 * 32];
  const int z = blockIdx.z;
  const long idxA = (SEL_MODE == 1) ? sel[z] : (SEL_MODE == 3 ? (z >> 1) : z);
  const long idxB = (SEL_MODE == 2) ? sel[z] : z;
  const unsigned short* A = A0 + idxA * sAz;
  const unsigned short* B = B0 + idxB * sBz;
  const float* bias = bias0;
  if (BIAS_MODE) {
    long idxBias = (SEL_MODE == 1 || SEL_MODE == 2) ? sel[z] : z;
    bias = bias0 + idxBias * sBiasz;
  }
  const int tid = threadIdx.x;
  const int lane = tid & 63;
  const int wid = tid >> 6;
  const int wr = wid >> 1, wc = wid & 1;
  const long rowBase = (long)blockIdx.y * 128;
  const long colBase = (long)blockIdx.x * 128;

  const int strow = lane >> 2;       // staging: row within 16-row group
  const int stcol = (lane & 3) * 8;  // staging: bf16 col offset

  f32x4 acc[4][4] = {};

  const int nk = K >> 5;
  for (int kt = 0; kt < nk; ++kt) {
    const long k0 = (long)kt << 5;
    const unsigned short* Ak;
    const unsigned short* Bk;
    if (SPLITK2 && k0 >= 1024) { Ak = A + segA + (k0 - 1024); Bk = B + segB + (k0 - 1024); }
    else                       { Ak = A + k0;                 Bk = B + k0; }
    __syncthreads();                       // LDS free from previous iter
    #pragma unroll
    for (int i = 0; i < 2; ++i) {
      const int r = wid * 32 + i * 16;     // wave-uniform LDS base row
      gload_lds16(Ak + (rowBase + r + strow) * 1024 + stcol, &As[r * 32]);
      gload_lds16(Bk + (colBase + r + strow) * 1024 + stcol, &Bs[r * 32]);
    }
    __syncthreads();                       // drains vmcnt: tiles visible
    bf16x8 areg[4], breg[4];
    #pragma unroll
    for (int m = 0; m < 4; ++m)
      areg[m] = *(const bf16x8*)&As[(wr * 64 + m * 16 + (lane & 15)) * 32 + (lane >> 4) * 8];
    #pragma unroll
    for (int n = 0; n < 4; ++n)
      breg[n] = *(const bf16x8*)&Bs[(wc * 64 + n * 16 + (lane & 15)) * 32 + (lane >> 4) * 8];
    #pragma unroll
    for (int m = 0; m < 4; ++m)
      #pragma unroll
      for (int n = 0; n < 4; ++n)
        acc[m][n] = __builtin_amdgcn_mfma_f32_16x16x32_bf16(areg[m], breg[n], acc[m][n], 0, 0, 0);
  }

  // epilogue: C/D layout col=lane&15, row=(lane>>4)*4+j  [m89-verified]
  unsigned short* Cb = (unsigned short*)C0 + (long)z * sCz;
  float* Cf = (float*)C0 + (long)z * sCz;
  const long crow0 = rowBase + wr * 64;
  const long ccol0 = colBase + wc * 64;
  #pragma unroll
  for (int m = 0; m < 4; ++m) {
    #pragma unroll
    for (int j = 0; j < 4; ++j) {
      const long row = crow0 + m * 16 + (lane >> 4) * 4 + j;
      const float brow = (BIAS_MODE == 2) ? bias[row] : 0.f;
      #pragma unroll
      for (int n = 0; n < 4; ++n) {
        const long col = ccol0 + n * 16 + (lane & 15);
        float v = acc[m][n][j] + brow;
        if (BIAS_MODE == 1) v += bias[col];
        if (OUT_BF16) Cb[row * 1024 + col] = f2bf(v);
        else          Cf[row * 1024 + col] = v;
      }
    }
  }
}

extern "C" void kernel_launch(void* const* d_in, const int* in_sizes, int n_in,
                              void* d_out, int out_size, void* d_ws, size_t ws_size,
                              hipStream_t stream) {
  (void)in_sizes; (void)n_in; (void)out_size; (void)ws_size;
  const float* Q   = (const float*)d_in[0];
  const float* src = (const float*)d_in[1];
  const float* Wq  = (const float*)d_in[2];
  const float* bq  = (const float*)d_in[3];
  const float* Wk  = (const float*)d_in[4];
  const float* bk  = (const float*)d_in[5];
  const float* Wv  = (const float*)d_in[6];
  const float* bv  = (const float*)d_in[7];
  const float* Wm1 = (const float*)d_in[8];
  const float* bm1 = (const float*)d_in[9];
  const float* Wm2 = (const float*)d_in[10];
  const float* bm2 = (const float*)d_in[11];
  const float* Wo  = (const float*)d_in[12];
  const float* bo  = (const float*)d_in[13];
  float* out = (float*)d_out;

  char* ws = (char*)d_ws;
  const long MBb = 1024L * 1024;  // bytes
  const long ME  = 1024L * 1024;  // elements per [1024][1024] slab
  // Region [0,64MB): staging-phase buffers, all dead before Sbuf (G4) writes over them.
  unsigned short* Qbf   = (unsigned short*)(ws);             // 16 MB, dead after G1
  unsigned short* srcbf = (unsigned short*)(ws + 16 * MBb);  // 32 MB, dead after G3
  unsigned short* Wkbf  = (unsigned short*)(ws + 48 * MBb);  //  8 MB, dead after G2
  unsigned short* Wvbf  = (unsigned short*)(ws + 56 * MBb);  //  8 MB, dead after G3
  float*          Sbuf  = (float*)(ws);                      // 64 MB fp32 logits (G4+)
  unsigned short* Qpbf  = (unsigned short*)(ws + 64 * MBb);  // 16 MB
  unsigned short* Wqbf  = (unsigned short*)(ws + 80 * MBb);  //  2 MB
  unsigned short* Wobf  = (unsigned short*)(ws + 82 * MBb);  //  2 MB
  unsigned short* Kbf   = (unsigned short*)(ws + 84 * MBb);  // 32 MB
  unsigned short* Vtbf  = (unsigned short*)(ws + 116 * MBb); // 32 MB
  unsigned short* Pbf   = (unsigned short*)(ws + 148 * MBb); // 32 MB
  unsigned short* AObf  = (unsigned short*)(ws + 180 * MBb); // 16 MB
  float* Qmean  = (float*)(ws + 196 * MBb);
  float* pooled = (float*)(ws + 196 * MBb + 32 * 1024);
  float* hbuf   = (float*)(ws + 196 * MBb + 64 * 1024);
  int*   sel    = (int*)(ws + 196 * MBb + 96 * 1024);
  float* wsel   = (float*)(ws + 196 * MBb + 96 * 1024 + 256);
  // total ws use: ~196.1 MB

  // bf16 conversions of dense operands
  convert_bf16_kernel<<<4096, 256, 0, stream>>>(Q, Qbf);
  convert_bf16_kernel<<<512,  256, 0, stream>>>(Wq, Wqbf);
  convert_bf16_kernel<<<2048, 256, 0, stream>>>(Wk, Wkbf);
  convert_bf16_kernel<<<2048, 256, 0, stream>>>(Wv, Wvbf);
  convert_bf16_kernel<<<512,  256, 0, stream>>>(Wo, Wobf);

  // gate path, pure fp32 (exact top-k match with reference)
  zero_kernel<<<32, 256, 0, stream>>>(Qmean);
  qmean_kernel<<<dim3(4, 8, 16), 256, 0, stream>>>(Q, Qmean);
  matvec_kernel<0><<<2048, 256, 0, stream>>>(Qmean, Wq, bq, pooled);
  matvec_kernel<1><<<2048, 256, 0, stream>>>(pooled, Wm1, bm1, hbuf);
  gate_kernel<<<1, 256, 0, stream>>>(hbuf, Wm2, bm2, sel, wsel);

  // gather+convert only the top-2 selected src[p][b] slices
  select_convert_kernel<<<dim3(512, 16), 256, 0, stream>>>(src, sel, srcbf);

  // G1: Qp = Q·Wq^T + bq  -> bf16 [8192,1024]
  gemm_nt<1,1,0,0><<<dim3(8, 64, 1), 256, 0, stream>>>(Qbf, 0, 0, Wqbf, 0, 0, bq, 0, Qpbf, 0, nullptr, 1024);
  // G2: K[z] = src_sel[z]·Wk[p]^T + bk[p] -> bf16 [LK,D]
  gemm_nt<1,1,2,0><<<dim3(8, 8, 16), 256, 0, stream>>>(srcbf, ME, 0, Wkbf, ME, 0, bk, D_, Kbf, ME, sel, 1024);
  // G3: Vt[z] = Wv[p]·src_sel[z]^T + bv[p] (row-bias) -> bf16 [D,LK]
  gemm_nt<2,1,1,0><<<dim3(8, 8, 16), 256, 0, stream>>>(Wvbf, ME, 0, srcbf, ME, 0, bv, D_, Vtbf, ME, sel, 1024);
  // G4: S[z] = Qp[b]·K[z]^T -> fp32 logits (scale folded into softmax)
  gemm_nt<0,0,3,0><<<dim3(8, 8, 16), 256, 0, stream>>>(Qpbf, ME, 0, Kbf, ME, 0, nullptr, 0, Sbuf, ME, nullptr, 1024);
  // softmax rows, fold 1/32 scale and gate weight, emit bf16 P
  softmax_kernel<<<dim3(256, 16), 256, 0, stream>>>(Sbuf, Pbf, wsel);
  // G5: AO[b] = sum_s P[b,s]·Vt[b,s]^T  (K=2048 over two slots) -> bf16
  gemm_nt<0,1,0,1><<<dim3(8, 8, 8), 256, 0, stream>>>(Pbf, 2 * ME, ME, Vtbf, 2 * ME, ME, nullptr, 0, AObf, ME, nullptr, 2048);
  // G6: out = AO·Wo^T + bo -> fp32 output
  gemm_nt<1,0,0,0><<<dim3(8, 64, 1), 256, 0, stream>>>(AObf, 0, 0, Wobf, 0, 0, bo, 0, out, 0, nullptr, 1024);
}

// Round 2
// 621.465 us; speedup vs baseline: 1.0252x; 1.0252x over previous
//
#include <hip/hip_runtime.h>

#define D_  1024
#define B_  8
#define P_  4
#define LQk 1024
#define LKk 1024

typedef __attribute__((ext_vector_type(8))) short bf16x8;
typedef __attribute__((ext_vector_type(4))) float f32x4;
typedef __attribute__((ext_vector_type(8))) unsigned short ushort8v;

__device__ __forceinline__ unsigned short f2bf(float f) {
  unsigned int u = __float_as_uint(f);
  u += 0x7FFFu + ((u >> 16) & 1u);           // RNE
  return (unsigned short)(u >> 16);
}

__device__ __forceinline__ void gload_lds16(const void* g, void* l) {
  __builtin_amdgcn_global_load_lds(
      (const __attribute__((address_space(1))) unsigned int*)g,
      (__attribute__((address_space(3))) unsigned int*)l, 16, 0, 0);
}

#define SBAR() do { __builtin_amdgcn_sched_barrier(0); __builtin_amdgcn_s_barrier(); __builtin_amdgcn_sched_barrier(0); } while (0)

// ---------------- fp32 -> bf16 convert (exact grid, 8 elems/thread) ----------------
__global__ __launch_bounds__(256) void convert_bf16_kernel(const float* __restrict__ in,
                                                           unsigned short* __restrict__ out) {
  long i = ((long)blockIdx.x * 256 + threadIdx.x) * 8;
  float4 v0 = *(const float4*)(in + i);
  float4 v1 = *(const float4*)(in + i + 4);
  ushort8v r;
  r[0] = f2bf(v0.x); r[1] = f2bf(v0.y); r[2] = f2bf(v0.z); r[3] = f2bf(v0.w);
  r[4] = f2bf(v1.x); r[5] = f2bf(v1.y); r[6] = f2bf(v1.z); r[7] = f2bf(v1.w);
  *(ushort8v*)(out + i) = r;
}

__global__ __launch_bounds__(256) void zero_kernel(float* __restrict__ p) {
  p[blockIdx.x * 256 + threadIdx.x] = 0.f;
}

// Qmean[b][d] = (1/LQ) sum_q Q[b,q,d] ; grid (4, 8, 16), atomics across q-chunks
__global__ __launch_bounds__(256) void qmean_kernel(const float* __restrict__ Q,
                                                    float* __restrict__ Qm) {
  int d = blockIdx.x * 256 + threadIdx.x;
  int b = blockIdx.y;
  int q0 = blockIdx.z * 64;
  const float* q = Q + ((long)b * LQk + q0) * D_ + d;
  float s = 0.f;
  #pragma unroll 8
  for (int i = 0; i < 64; ++i) s += q[(long)i * D_];
  atomicAdd(&Qm[b * D_ + d], s * (1.0f / 1024.0f));
}

// out[b][e] = act(X[b]·W[e] + bias[e]); one wave per output; grid 2048 x 256thr
template<int RELU>
__global__ __launch_bounds__(256) void matvec_kernel(const float* __restrict__ X,
                                                     const float* __restrict__ W,
                                                     const float* __restrict__ bias,
                                                     float* __restrict__ out) {
  int g = blockIdx.x * 4 + (threadIdx.x >> 6);
  int lane = threadIdx.x & 63;
  int b = g >> 10, e = g & 1023;
  const float* x = X + b * D_;
  const float* w = W + (long)e * D_;
  float s = 0.f;
  #pragma unroll
  for (int k = lane * 4; k < D_; k += 256) {
    float4 xv = *(const float4*)(x + k);
    float4 wv = *(const float4*)(w + k);
    s += xv.x * wv.x + xv.y * wv.y + xv.z * wv.z + xv.w * wv.w;
  }
  #pragma unroll
  for (int o = 32; o; o >>= 1) s += __shfl_xor(s, o, 64);
  if (lane == 0) {
    s += bias[e];
    if (RELU) s = fmaxf(s, 0.f);
    out[b * D_ + e] = s;
  }
}

// path logits -> softmax -> top-2 (strict >, ties to lower index = lax.top_k) -> renormalized weights
__global__ __launch_bounds__(256) void gate_kernel(const float* __restrict__ h,
                                                   const float* __restrict__ Wm2,
                                                   const float* __restrict__ bm2,
                                                   int* __restrict__ sel,
                                                   float* __restrict__ wsel) {
  __shared__ float lg[B_][P_];
  int lane = threadIdx.x & 63, wid = threadIdx.x >> 6;
  #pragma unroll
  for (int i = 0; i < 8; ++i) {
    int pair = wid * 8 + i;
    int b = pair >> 2, p = pair & 3;
    const float* x = h + b * D_;
    const float* w = Wm2 + p * D_;
    float s = 0.f;
    for (int k = lane; k < D_; k += 64) s += x[k] * w[k];
    #pragma unroll
    for (int o = 32; o; o >>= 1) s += __shfl_xor(s, o, 64);
    if (lane == 0) lg[b][p] = s + bm2[p];
  }
  __syncthreads();
  if (threadIdx.x < B_) {
    int b = threadIdx.x;
    float v0 = lg[b][0], v1 = lg[b][1], v2 = lg[b][2], v3 = lg[b][3];
    float m = fmaxf(fmaxf(v0, v1), fmaxf(v2, v3));
    float e[4];
    e[0] = __expf(v0 - m); e[1] = __expf(v1 - m);
    e[2] = __expf(v2 - m); e[3] = __expf(v3 - m);
    float sum = e[0] + e[1] + e[2] + e[3];
    int p0 = 0;
    for (int p = 1; p < 4; ++p) if (e[p] > e[p0]) p0 = p;
    int p1 = -1;
    for (int p = 0; p < 4; ++p) { if (p == p0) continue; if (p1 < 0 || e[p] > e[p1]) p1 = p; }
    float s0 = e[p0] / sum, s1 = e[p1] / sum;
    float dn = s0 + s1 + 1e-8f;
    sel[b * 2] = p0; sel[b * 2 + 1] = p1;
    wsel[b * 2] = s0 / dn; wsel[b * 2 + 1] = s1 / dn;
  }
}

// copy+convert selected src[p][b] slices to bf16; grid (512, 16)
__global__ __launch_bounds__(256) void select_convert_kernel(const float* __restrict__ src,
                                                             const int* __restrict__ sel,
                                                             unsigned short* __restrict__ out) {
  int z = blockIdx.y; int b = z >> 1; int p = sel[z];
  const float* s = src + ((long)p * B_ + b) * (1024L * 1024);
  unsigned short* o = out + (long)z * (1024L * 1024);
  long i = ((long)blockIdx.x * 256 + threadIdx.x) * 8;
  float4 v0 = *(const float4*)(s + i);
  float4 v1 = *(const float4*)(s + i + 4);
  ushort8v r;
  r[0] = f2bf(v0.x); r[1] = f2bf(v0.y); r[2] = f2bf(v0.z); r[3] = f2bf(v0.w);
  r[4] = f2bf(v1.x); r[5] = f2bf(v1.y); r[6] = f2bf(v1.z); r[7] = f2bf(v1.w);
  *(ushort8v*)(o + i) = r;
}

// row softmax over 1024 fp32 logits, fold 1/sqrt(D) and gate weight, emit bf16
__global__ __launch_bounds__(256) void softmax_kernel(const float* __restrict__ S,
                                                      unsigned short* __restrict__ P,
                                                      const float* __restrict__ wsel) {
  int z = blockIdx.y;
  int row = blockIdx.x * 4 + (threadIdx.x >> 6);
  int lane = threadIdx.x & 63;
  const float* s = S + ((long)z * LQk + row) * LKk;
  float4 v[4];
  #pragma unroll
  for (int i = 0; i < 4; ++i) v[i] = *(const float4*)(s + (lane + i * 64) * 4);
  float m = -1e30f;
  #pragma unroll
  for (int i = 0; i < 4; ++i)
    m = fmaxf(m, fmaxf(fmaxf(v[i].x, v[i].y), fmaxf(v[i].z, v[i].w)));
  #pragma unroll
  for (int o = 32; o; o >>= 1) m = fmaxf(m, __shfl_xor(m, o, 64));
  const float sc = 0.03125f;  // 1/sqrt(1024), exact
  float sum = 0.f;
  #pragma unroll
  for (int i = 0; i < 4; ++i) {
    v[i].x = __expf((v[i].x - m) * sc);
    v[i].y = __expf((v[i].y - m) * sc);
    v[i].z = __expf((v[i].z - m) * sc);
    v[i].w = __expf((v[i].w - m) * sc);
    sum += v[i].x + v[i].y + v[i].z + v[i].w;
  }
  #pragma unroll
  for (int o = 32; o; o >>= 1) sum += __shfl_xor(sum, o, 64);
  float wf = wsel[z] / sum;
  unsigned short* p = P + ((long)z * LQk + row) * LKk;
  #pragma unroll
  for (int i = 0; i < 4; ++i) {
    ushort4 r;
    r.x = f2bf(v[i].x * wf); r.y = f2bf(v[i].y * wf);
    r.z = f2bf(v[i].z * wf); r.w = f2bf(v[i].w * wf);
    *(ushort4*)(p + (lane + i * 64) * 4) = r;
  }
}

// ============ 256x256 8-phase NT GEMM: C[M,N] = A[M,K]·B[N,K]^T (+bias) ============
// BK=64, 8 waves (2Mx4N), double-buffered LDS (128 KiB), counted vmcnt(4),
// XOR LDS swizzle (gran ^= row&7) applied via pre-permuted global source (rule #21).
// SEL_MODE: 0 idx=z, 1 A by sel[z], 2 B by sel[z], 3 A by z>>1. SWZ: z->XCD block swizzle.
// SPLITK2: K=2048 over two 1M-elem segments. N==1024 always; non-SWZ grid = 4 x (M/256).
template<int BIAS_MODE, int OUT_BF16, int SEL_MODE, int SPLITK2, int SWZ>
__global__ __launch_bounds__(512, 2) void gemm256(
    const unsigned short* __restrict__ A0, long sAz, long segA,
    const unsigned short* __restrict__ B0, long sBz, long segB,
    const float* __restrict__ bias0, long sBiasz,
    void* __restrict__ C0, long sCz,
    const int* __restrict__ sel, int K) {
  __shared__ unsigned short As[2][256 * 64];
  __shared__ unsigned short Bs[2][256 * 64];
  const int id = blockIdx.x;
  int tx, ty, z;
  if (SWZ) {  // blocks of one z land on one XCD (id%8): L2 working set ~4MB/XCD
    int m = id & 7, j = id >> 3;
    int t = j & 15;
    z = (j >> 4) * 8 + m;
    tx = t & 3; ty = t >> 2;
  } else {
    tx = id & 3; ty = id >> 2; z = 0;
  }
  const long idxA = (SEL_MODE == 1) ? sel[z] : (SEL_MODE == 3 ? (z >> 1) : z);
  const long idxB = (SEL_MODE == 2) ? sel[z] : z;
  const unsigned short* A = A0 + idxA * sAz;
  const unsigned short* B = B0 + idxB * sBz;
  const float* bias = bias0;
  if (BIAS_MODE) bias = bias0 + ((SEL_MODE == 1 || SEL_MODE == 2) ? (long)sel[z] : (long)z) * sBiasz;

  const int tid = threadIdx.x, lane = tid & 63, wid = tid >> 6;
  const int wr = wid >> 2, wc = wid & 3;          // 2x4 wave grid; wave owns 128x64 of C
  const long rowBase = (long)ty * 256, colBase = (long)tx * 256;

  // staging: one call = 1KB wave-write (8 rows x 128B), lane l -> row +(l>>3), dest gran l&7,
  // source gran = (l&7)^(l>>3)  (inverse of read-side swizzle; rows are 0 mod 8)
  const int srow = lane >> 3;
  const int sgran = ((lane & 7) ^ (lane >> 3)) * 8;
  // fragment reads: row r = ...+(lane&15); granule = (kk*4 + lane>>4) ^ (r&7), r&7 == lane&7
  const int aOff = (wr * 128 + (lane & 15)) * 64;
  const int bOff = (wc * 64 + (lane & 15)) * 64;
  const int gk0 = ((lane >> 4) ^ (lane & 7)) * 8;
  const int gk1 = (((lane >> 4) + 4) ^ (lane & 7)) * 8;

  const int NKT = K >> 6;      // 64-wide K tiles
  const int T = NKT >> 1;      // iterations (2 tiles each)

  f32x4 acc[8][4] = {};

#define STG(ISB, HALF, KT, BUF) do {                                                   \
    if ((KT) < NKT) {                                                                  \
      const unsigned short* gp_ = (ISB) ? B : A;                                       \
      const long seg_ = (ISB) ? segB : segA;                                           \
      const long kc_ = (SPLITK2 && (KT) >= 16) ? (seg_ + (long)((KT) - 16) * 64)       \
                                               : ((long)(KT) * 64);                    \
      const int rb_ = (HALF) * 128 + wid * 16;                                         \
      const long gr_ = ((ISB) ? colBase : rowBase) + rb_ + srow;                       \
      const unsigned short* g0_ = gp_ + gr_ * 1024 + kc_ + sgran;                      \
      unsigned short* l0_ = ((ISB) ? &Bs[BUF][0] : &As[BUF][0]) + rb_ * 64;            \
      gload_lds16(g0_, l0_);                                                           \
      gload_lds16(g0_ + 8 * 1024, l0_ + 8 * 64);                                       \
    }                                                                                  \
  } while (0)

#define LDA(BUF, GK, MF) (*(const bf16x8*)&As[BUF][aOff + (MF) * 1024 + (GK)])
#define LDB(BUF, GK, NF) (*(const bf16x8*)&Bs[BUF][bOff + (NF) * 1024 + (GK)])

#define MF16(AV, BV, NLO) do {                                                         \
    __builtin_amdgcn_s_setprio(1);                                                     \
    _Pragma("unroll")                                                                  \
    for (int mf_ = 0; mf_ < 8; ++mf_) {                                                \
      acc[mf_][NLO]     = __builtin_amdgcn_mfma_f32_16x16x32_bf16(AV[mf_], BV[NLO],    \
                                                                  acc[mf_][NLO], 0, 0, 0); \
      acc[mf_][(NLO)+1] = __builtin_amdgcn_mfma_f32_16x16x32_bf16(AV[mf_], BV[(NLO)+1],\
                                                                  acc[mf_][(NLO)+1], 0, 0, 0); \
    }                                                                                  \
    __builtin_amdgcn_s_setprio(0);                                                     \
  } while (0)

  // prologue: tile0 (buf0) fully + tile1 (buf1) half0 A,B -> 12 loads in flight
  STG(0, 0, 0, 0); STG(1, 0, 0, 0); STG(0, 1, 0, 0); STG(1, 1, 0, 0);
  STG(0, 0, 1, 1); STG(1, 0, 1, 1);
  __builtin_amdgcn_sched_barrier(0);
  asm volatile("s_waitcnt vmcnt(4)" ::: "memory");   // tile0 landed, tile1-h0 in flight
  __builtin_amdgcn_s_barrier();
  __builtin_amdgcn_sched_barrier(0);

  for (int t = 0; t < T; ++t) {
    const int o = 2 * t + 1, n0 = 2 * t + 2, n1 = 2 * t + 3;
    bf16x8 a0[8], a1[8], b0[4], b1[4];
    // ---- even tile (buf0), phases 1-4 ----
    #pragma unroll
    for (int i = 0; i < 8; ++i) a0[i] = LDA(0, gk0, i);
    #pragma unroll
    for (int i = 0; i < 4; ++i) b0[i] = LDB(0, gk0, i);
    STG(0, 1, o, 1);                 // A-h1 of odd tile -> buf1 (reads of buf1 done last iter)
    SBAR();
    MF16(a0, b0, 0);
    SBAR();
    #pragma unroll
    for (int i = 0; i < 8; ++i) a1[i] = LDA(0, gk1, i);
    #pragma unroll
    for (int i = 0; i < 4; ++i) b1[i] = LDB(0, gk1, i);
    STG(1, 1, o, 1);                 // B-h1 of odd tile -> buf1
    SBAR();
    MF16(a0, b0, 2);
    SBAR();
    STG(0, 0, n0, 0);                // A-h0 of tile n0 -> buf0 (buf0 reads finished ph1-2)
    SBAR();
    MF16(a1, b1, 0);
    SBAR();
    STG(1, 0, n0, 0);                // B-h0 of tile n0 -> buf0
    SBAR();
    MF16(a1, b1, 2);
    __builtin_amdgcn_sched_barrier(0);
    if (t == T - 1) { asm volatile("s_waitcnt vmcnt(0)" ::: "memory"); }
    else            { asm volatile("s_waitcnt vmcnt(4)" ::: "memory"); }  // odd tile landed
    __builtin_amdgcn_s_barrier();
    __builtin_amdgcn_sched_barrier(0);
    // ---- odd tile (buf1), phases 5-8 ----
    #pragma unroll
    for (int i = 0; i < 8; ++i) a0[i] = LDA(1, gk0, i);
    #pragma unroll
    for (int i = 0; i < 4; ++i) b0[i] = LDB(1, gk0, i);
    STG(0, 1, n0, 0);                // A-h1 of tile n0 -> buf0
    SBAR();
    MF16(a0, b0, 0);
    SBAR();
    #pragma unroll
    for (int i = 0; i < 8; ++i) a1[i] = LDA(1, gk1, i);
    #pragma unroll
    for (int i = 0; i < 4; ++i) b1[i] = LDB(1, gk1, i);
    STG(1, 1, n0, 0);                // B-h1 of tile n0 -> buf0
    SBAR();
    MF16(a0, b0, 2);
    SBAR();
    STG(0, 0, n1, 1);                // A-h0 of tile n1 -> buf1 (buf1 reads finished ph5-6)
    SBAR();
    MF16(a1, b1, 0);
    SBAR();
    STG(1, 0, n1, 1);                // B-h0 of tile n1 -> buf1
    SBAR();
    MF16(a1, b1, 2);
    if (t < T - 1) {
      __builtin_amdgcn_sched_barrier(0);
      asm volatile("s_waitcnt vmcnt(4)" ::: "memory");  // tile n0 landed for next iter
      __builtin_amdgcn_s_barrier();
      __builtin_amdgcn_sched_barrier(0);
    }
  }
#undef STG
#undef LDA
#undef LDB
#undef MF16

  // epilogue: C/D layout col=lane&15, row=(lane>>4)*4+j  [m89-verified]
  unsigned short* Cb = (unsigned short*)C0 + (long)z * sCz;
  float* Cf = (float*)C0 + (long)z * sCz;
  const long crow0 = rowBase + wr * 128;
  const long ccol0 = colBase + wc * 64;
  #pragma unroll
  for (int mf = 0; mf < 8; ++mf) {
    #pragma unroll
    for (int j = 0; j < 4; ++j) {
      const long row = crow0 + mf * 16 + (lane >> 4) * 4 + j;
      const float brow = (BIAS_MODE == 2) ? bias[row] : 0.f;
      #pragma unroll
      for (int nf = 0; nf < 4; ++nf) {
        const long col = ccol0 + nf * 16 + (lane & 15);
        float v = acc[mf][nf][j] + brow;
        if (BIAS_MODE == 1) v += bias[col];
        if (OUT_BF16) Cb[row * 1024 + col] = f2bf(v);
        else          Cf[row * 1024 + col] = v;
      }
    }
  }
}

extern "C" void kernel_launch(void* const* d_in, const int* in_sizes, int n_in,
                              void* d_out, int out_size, void* d_ws, size_t ws_size,
                              hipStream_t stream) {
  (void)in_sizes; (void)n_in; (void)out_size; (void)ws_size;
  const float* Q   = (const float*)d_in[0];
  const float* src = (const float*)d_in[1];
  const float* Wq  = (const float*)d_in[2];
  const float* bq  = (const float*)d_in[3];
  const float* Wk  = (const float*)d_in[4];
  const float* bk  = (const float*)d_in[5];
  const float* Wv  = (const float*)d_in[6];
  const float* bv  = (const float*)d_in[7];
  const float* Wm1 = (const float*)d_in[8];
  const float* bm1 = (const float*)d_in[9];
  const float* Wm2 = (const float*)d_in[10];
  const float* bm2 = (const float*)d_in[11];
  const float* Wo  = (const float*)d_in[12];
  const float* bo  = (const float*)d_in[13];
  float* out = (float*)d_out;

  char* ws = (char*)d_ws;
  const long MBb = 1024L * 1024;  // bytes
  const long ME  = 1024L * 1024;  // elements per [1024][1024] slab
  // Region [0,64MB): staging-phase buffers, all dead before Sbuf (G4) writes over them.
  unsigned short* Qbf   = (unsigned short*)(ws);             // 16 MB, dead after G1
  unsigned short* srcbf = (unsigned short*)(ws + 16 * MBb);  // 32 MB, dead after G3
  unsigned short* Wkbf  = (unsigned short*)(ws + 48 * MBb);  //  8 MB, dead after G2
  unsigned short* Wvbf  = (unsigned short*)(ws + 56 * MBb);  //  8 MB, dead after G3
  float*          Sbuf  = (float*)(ws);                      // 64 MB fp32 logits (G4+)
  unsigned short* Qpbf  = (unsigned short*)(ws + 64 * MBb);  // 16 MB
  unsigned short* Wqbf  = (unsigned short*)(ws + 80 * MBb);  //  2 MB
  unsigned short* Wobf  = (unsigned short*)(ws + 82 * MBb);  //  2 MB
  unsigned short* Kbf   = (unsigned short*)(ws + 84 * MBb);  // 32 MB
  unsigned short* Vtbf  = (unsigned short*)(ws + 116 * MBb); // 32 MB
  unsigned short* Pbf   = (unsigned short*)(ws + 148 * MBb); // 32 MB
  unsigned short* AObf  = (unsigned short*)(ws + 180 * MBb); // 16 MB
  float* Qmean  = (float*)(ws + 196 * MBb);
  float* pooled = (float*)(ws + 196 * MBb + 32 * 1024);
  float* hbuf   = (float*)(ws + 196 * MBb + 64 * 1024);
  int*   sel    = (int*)(ws + 196 * MBb + 96 * 1024);
  float* wsel   = (float*)(ws + 196 * MBb + 96 * 1024 + 256);

  // bf16 conversions of dense operands
  convert_bf16_kernel<<<4096, 256, 0, stream>>>(Q, Qbf);
  convert_bf16_kernel<<<512,  256, 0, stream>>>(Wq, Wqbf);
  convert_bf16_kernel<<<2048, 256, 0, stream>>>(Wk, Wkbf);
  convert_bf16_kernel<<<2048, 256, 0, stream>>>(Wv, Wvbf);
  convert_bf16_kernel<<<512,  256, 0, stream>>>(Wo, Wobf);

  // gate path, pure fp32 (exact top-k match with reference)
  zero_kernel<<<32, 256, 0, stream>>>(Qmean);
  qmean_kernel<<<dim3(4, 8, 16), 256, 0, stream>>>(Q, Qmean);
  matvec_kernel<0><<<2048, 256, 0, stream>>>(Qmean, Wq, bq, pooled);
  matvec_kernel<1><<<2048, 256, 0, stream>>>(pooled, Wm1, bm1, hbuf);
  gate_kernel<<<1, 256, 0, stream>>>(hbuf, Wm2, bm2, sel, wsel);

  // gather+convert only the top-2 selected src[p][b] slices
  select_convert_kernel<<<dim3(512, 16), 256, 0, stream>>>(src, sel, srcbf);

  // G1: Qp = Q·Wq^T + bq  -> bf16 [8192,1024]
  gemm256<1,1,0,0,0><<<128, 512, 0, stream>>>(Qbf, 0, 0, Wqbf, 0, 0, bq, 0, Qpbf, 0, nullptr, 1024);
  // G2: K[z] = src_sel[z]·Wk[p]^T + bk[p] -> bf16 [LK,D]
  gemm256<1,1,2,0,1><<<256, 512, 0, stream>>>(srcbf, ME, 0, Wkbf, ME, 0, bk, D_, Kbf, ME, sel, 1024);
  // G3: Vt[z] = Wv[p]·src_sel[z]^T + bv[p] (row-bias) -> bf16 [D,LK]
  gemm256<2,1,1,0,1><<<256, 512, 0, stream>>>(Wvbf, ME, 0, srcbf, ME, 0, bv, D_, Vtbf, ME, sel, 1024);
  // G4: S[z] = Qp[b]·K[z]^T -> fp32 logits (scale folded into softmax)
  gemm256<0,0,3,0,1><<<256, 512, 0, stream>>>(Qpbf, ME, 0, Kbf, ME, 0, nullptr, 0, Sbuf, ME, nullptr, 1024);
  // softmax rows, fold 1/32 scale and gate weight, emit bf16 P
  softmax_kernel<<<dim3(256, 16), 256, 0, stream>>>(Sbuf, Pbf, wsel);
  // G5: AO[b] = sum_s P[b,s]·Vt[b,s]^T  (K=2048 over two slots) -> bf16
  gemm256<0,1,0,1,1><<<128, 512, 0, stream>>>(Pbf, 2 * ME, ME, Vtbf, 2 * ME, ME, nullptr, 0, AObf, ME, nullptr, 2048);
  // G6: out = AO·Wo^T + bo -> fp32 output
  gemm256<1,0,0,0,0><<<128, 512, 0, stream>>>(AObf, 0, 0, Wobf, 0, 0, bo, 0, out, 0, nullptr, 1024);
}

// Round 3
// 583.000 us; speedup vs baseline: 1.0929x; 1.0660x over previous
//
#include <hip/hip_runtime.h>

#define D_  1024
#define B_  8
#define P_  4
#define LQk 1024
#define LKk 1024

typedef __attribute__((ext_vector_type(8))) short bf16x8;
typedef __attribute__((ext_vector_type(4))) float f32x4;
typedef __attribute__((ext_vector_type(8))) unsigned short ushort8v;

__device__ __forceinline__ unsigned short f2bf(float f) {
  unsigned int u = __float_as_uint(f);
  u += 0x7FFFu + ((u >> 16) & 1u);           // RNE
  return (unsigned short)(u >> 16);
}

__device__ __forceinline__ void gload_lds16(const void* g, void* l) {
  __builtin_amdgcn_global_load_lds(
      (const __attribute__((address_space(1))) unsigned int*)g,
      (__attribute__((address_space(3))) unsigned int*)l, 16, 0, 0);
}

// ---------------- fp32 -> bf16 convert (exact grid, 8 elems/thread) ----------------
__global__ __launch_bounds__(256) void convert_bf16_kernel(const float* __restrict__ in,
                                                           unsigned short* __restrict__ out) {
  long i = ((long)blockIdx.x * 256 + threadIdx.x) * 8;
  float4 v0 = *(const float4*)(in + i);
  float4 v1 = *(const float4*)(in + i + 4);
  ushort8v r;
  r[0] = f2bf(v0.x); r[1] = f2bf(v0.y); r[2] = f2bf(v0.z); r[3] = f2bf(v0.w);
  r[4] = f2bf(v1.x); r[5] = f2bf(v1.y); r[6] = f2bf(v1.z); r[7] = f2bf(v1.w);
  *(ushort8v*)(out + i) = r;
}

__global__ __launch_bounds__(256) void zero_kernel(float* __restrict__ p) {
  p[blockIdx.x * 256 + threadIdx.x] = 0.f;
}

// Qmean[b][d] = (1/LQ) sum_q Q[b,q,d] ; grid (4, 8, 16), atomics across q-chunks
__global__ __launch_bounds__(256) void qmean_kernel(const float* __restrict__ Q,
                                                    float* __restrict__ Qm) {
  int d = blockIdx.x * 256 + threadIdx.x;
  int b = blockIdx.y;
  int q0 = blockIdx.z * 64;
  const float* q = Q + ((long)b * LQk + q0) * D_ + d;
  float s = 0.f;
  #pragma unroll 8
  for (int i = 0; i < 64; ++i) s += q[(long)i * D_];
  atomicAdd(&Qm[b * D_ + d], s * (1.0f / 1024.0f));
}

// out[b][e] = act(X[b]·W[e] + bias[e]); one wave per output; grid 2048 x 256thr
template<int RELU>
__global__ __launch_bounds__(256) void matvec_kernel(const float* __restrict__ X,
                                                     const float* __restrict__ W,
                                                     const float* __restrict__ bias,
                                                     float* __restrict__ out) {
  int g = blockIdx.x * 4 + (threadIdx.x >> 6);
  int lane = threadIdx.x & 63;
  int b = g >> 10, e = g & 1023;
  const float* x = X + b * D_;
  const float* w = W + (long)e * D_;
  float s = 0.f;
  #pragma unroll
  for (int k = lane * 4; k < D_; k += 256) {
    float4 xv = *(const float4*)(x + k);
    float4 wv = *(const float4*)(w + k);
    s += xv.x * wv.x + xv.y * wv.y + xv.z * wv.z + xv.w * wv.w;
  }
  #pragma unroll
  for (int o = 32; o; o >>= 1) s += __shfl_xor(s, o, 64);
  if (lane == 0) {
    s += bias[e];
    if (RELU) s = fmaxf(s, 0.f);
    out[b * D_ + e] = s;
  }
}

// path logits -> softmax -> top-2 (strict >, ties to lower index = lax.top_k) -> renormalized weights
__global__ __launch_bounds__(256) void gate_kernel(const float* __restrict__ h,
                                                   const float* __restrict__ Wm2,
                                                   const float* __restrict__ bm2,
                                                   int* __restrict__ sel,
                                                   float* __restrict__ wsel) {
  __shared__ float lg[B_][P_];
  int lane = threadIdx.x & 63, wid = threadIdx.x >> 6;
  #pragma unroll
  for (int i = 0; i < 8; ++i) {
    int pair = wid * 8 + i;
    int b = pair >> 2, p = pair & 3;
    const float* x = h + b * D_;
    const float* w = Wm2 + p * D_;
    float s = 0.f;
    for (int k = lane; k < D_; k += 64) s += x[k] * w[k];
    #pragma unroll
    for (int o = 32; o; o >>= 1) s += __shfl_xor(s, o, 64);
    if (lane == 0) lg[b][p] = s + bm2[p];
  }
  __syncthreads();
  if (threadIdx.x < B_) {
    int b = threadIdx.x;
    float v0 = lg[b][0], v1 = lg[b][1], v2 = lg[b][2], v3 = lg[b][3];
    float m = fmaxf(fmaxf(v0, v1), fmaxf(v2, v3));
    float e[4];
    e[0] = __expf(v0 - m); e[1] = __expf(v1 - m);
    e[2] = __expf(v2 - m); e[3] = __expf(v3 - m);
    float sum = e[0] + e[1] + e[2] + e[3];
    int p0 = 0;
    for (int p = 1; p < 4; ++p) if (e[p] > e[p0]) p0 = p;
    int p1 = -1;
    for (int p = 0; p < 4; ++p) { if (p == p0) continue; if (p1 < 0 || e[p] > e[p1]) p1 = p; }
    float s0 = e[p0] / sum, s1 = e[p1] / sum;
    float dn = s0 + s1 + 1e-8f;
    sel[b * 2] = p0; sel[b * 2 + 1] = p1;
    wsel[b * 2] = s0 / dn; wsel[b * 2 + 1] = s1 / dn;
  }
}

// copy+convert selected src[p][b] slices to bf16; grid (512, 16)
__global__ __launch_bounds__(256) void select_convert_kernel(const float* __restrict__ src,
                                                             const int* __restrict__ sel,
                                                             unsigned short* __restrict__ out) {
  int z = blockIdx.y; int b = z >> 1; int p = sel[z];
  const float* s = src + ((long)p * B_ + b) * (1024L * 1024);
  unsigned short* o = out + (long)z * (1024L * 1024);
  long i = ((long)blockIdx.x * 256 + threadIdx.x) * 8;
  float4 v0 = *(const float4*)(s + i);
  float4 v1 = *(const float4*)(s + i + 4);
  ushort8v r;
  r[0] = f2bf(v0.x); r[1] = f2bf(v0.y); r[2] = f2bf(v0.z); r[3] = f2bf(v0.w);
  r[4] = f2bf(v1.x); r[5] = f2bf(v1.y); r[6] = f2bf(v1.z); r[7] = f2bf(v1.w);
  *(ushort8v*)(o + i) = r;
}

// row softmax over 1024 fp32 logits, fold 1/sqrt(D) and gate weight, emit bf16
__global__ __launch_bounds__(256) void softmax_kernel(const float* __restrict__ S,
                                                      unsigned short* __restrict__ P,
                                                      const float* __restrict__ wsel) {
  int z = blockIdx.y;
  int row = blockIdx.x * 4 + (threadIdx.x >> 6);
  int lane = threadIdx.x & 63;
  const float* s = S + ((long)z * LQk + row) * LKk;
  float4 v[4];
  #pragma unroll
  for (int i = 0; i < 4; ++i) v[i] = *(const float4*)(s + (lane + i * 64) * 4);
  float m = -1e30f;
  #pragma unroll
  for (int i = 0; i < 4; ++i)
    m = fmaxf(m, fmaxf(fmaxf(v[i].x, v[i].y), fmaxf(v[i].z, v[i].w)));
  #pragma unroll
  for (int o = 32; o; o >>= 1) m = fmaxf(m, __shfl_xor(m, o, 64));
  const float sc = 0.03125f;  // 1/sqrt(1024), exact
  float sum = 0.f;
  #pragma unroll
  for (int i = 0; i < 4; ++i) {
    v[i].x = __expf((v[i].x - m) * sc);
    v[i].y = __expf((v[i].y - m) * sc);
    v[i].z = __expf((v[i].z - m) * sc);
    v[i].w = __expf((v[i].w - m) * sc);
    sum += v[i].x + v[i].y + v[i].z + v[i].w;
  }
  #pragma unroll
  for (int o = 32; o; o >>= 1) sum += __shfl_xor(sum, o, 64);
  float wf = wsel[z] / sum;
  unsigned short* p = P + ((long)z * LQk + row) * LKk;
  #pragma unroll
  for (int i = 0; i < 4; ++i) {
    ushort4 r;
    r.x = f2bf(v[i].x * wf); r.y = f2bf(v[i].y * wf);
    r.z = f2bf(v[i].z * wf); r.w = f2bf(v[i].w * wf);
    *(ushort4*)(p + (lane + i * 64) * 4) = r;
  }
}

// AO[b] = bf16(part[2b] + part[2b+1]); grid (1024, 8)
__global__ __launch_bounds__(256) void combine_kernel(const float* __restrict__ S,
                                                      unsigned short* __restrict__ AO) {
  int b = blockIdx.y;
  long i = ((long)blockIdx.x * 256 + threadIdx.x) * 4;
  const float* p0 = S + (long)(2 * b) * (1024L * 1024) + i;
  const float* p1 = S + (long)(2 * b + 1) * (1024L * 1024) + i;
  float4 v0 = *(const float4*)p0;
  float4 v1 = *(const float4*)p1;
  ushort4 r;
  r.x = f2bf(v0.x + v1.x); r.y = f2bf(v0.y + v1.y);
  r.z = f2bf(v0.z + v1.z); r.w = f2bf(v0.w + v1.w);
  *(ushort4*)(AO + (long)b * (1024L * 1024) + i) = r;
}

// ============ 256x256 8-phase NT GEMM: C[M,N] = A[M,K]·B[N,K]^T (+bias) ============
// BK=64, 8 waves (2Mx4N), double-buffered LDS, counted vmcnt(4) at tile boundaries ONLY,
// bare s_barriers (no sched walls — m141), XOR LDS swizzle via pre-permuted global source.
// Hazard discipline: every segment's STG targets the buffer NOT read in that segment.
template<int BIAS_MODE, int OUT_BF16, int SEL_MODE, int SWZ>
__global__ __launch_bounds__(512, 2) void gemm256(
    const unsigned short* __restrict__ A0, long sAz,
    const unsigned short* __restrict__ B0, long sBz,
    const float* __restrict__ bias0, long sBiasz,
    void* __restrict__ C0, long sCz,
    const int* __restrict__ sel, int K) {
  __shared__ unsigned short As[2][256 * 64];
  __shared__ unsigned short Bs[2][256 * 64];
  const int id = blockIdx.x;
  int tx, ty, z;
  if (SWZ) {  // all 16 tile-blocks of one z land on one XCD (id%8): ~4MB L2 set
    int m = id & 7, j = id >> 3;
    int t = j & 15;
    z = (j >> 4) * 8 + m;
    tx = t & 3; ty = t >> 2;
  } else {
    tx = id & 3; ty = id >> 2; z = 0;
  }
  const long idxA = (SEL_MODE == 1) ? sel[z] : (SEL_MODE == 3 ? (z >> 1) : z);
  const long idxB = (SEL_MODE == 2) ? sel[z] : z;
  const unsigned short* A = A0 + idxA * sAz;
  const unsigned short* B = B0 + idxB * sBz;
  const float* bias = bias0;
  if (BIAS_MODE) bias = bias0 + ((SEL_MODE == 1 || SEL_MODE == 2) ? (long)sel[z] : (long)z) * sBiasz;

  const int tid = threadIdx.x, lane = tid & 63, wid = tid >> 6;
  const int wr = wid >> 2, wc = wid & 3;          // 2x4 wave grid; wave owns 128x64 of C
  const long rowBase = (long)ty * 256, colBase = (long)tx * 256;

  // staging: one gload = 1KB wave-write (8 rows x 128B); source gran pre-permuted
  // by the read-side XOR so LDS stays linear (rule #21).
  const int srow = lane >> 3;
  const int sgran = ((lane & 7) ^ (lane >> 3)) * 8;
  // fragment reads: row r = ...+(lane&15); granule = (kk*4 + lane>>4) ^ (r&7)
  const int aOff = (wr * 128 + (lane & 15)) * 64;
  const int bOff = (wc * 64 + (lane & 15)) * 64;
  const int gk0 = ((lane >> 4) ^ (lane & 7)) * 8;
  const int gk1 = (((lane >> 4) + 4) ^ (lane & 7)) * 8;

  const int NKT = K >> 6;      // 64-wide K tiles
  const int T = NKT >> 1;      // iterations (2 tiles each)

  f32x4 acc[8][4] = {};

#define STG(ISB, HALF, KT, BUF) do {                                                   \
    if ((KT) < NKT) {                                                                  \
      const unsigned short* gp_ = (ISB) ? B : A;                                       \
      const long kc_ = (long)(KT) * 64;                                                \
      const int rb_ = (HALF) * 128 + wid * 16;                                         \
      const long gr_ = ((ISB) ? colBase : rowBase) + rb_ + srow;                       \
      const unsigned short* g0_ = gp_ + gr_ * 1024 + kc_ + sgran;                      \
      unsigned short* l0_ = ((ISB) ? &Bs[BUF][0] : &As[BUF][0]) + rb_ * 64;            \
      gload_lds16(g0_, l0_);                                                           \
      gload_lds16(g0_ + 8 * 1024, l0_ + 8 * 64);                                       \
    }                                                                                  \
  } while (0)

#define LDA(BUF, GK, MF) (*(const bf16x8*)&As[BUF][aOff + (MF) * 1024 + (GK)])
#define LDB(BUF, GK, NF) (*(const bf16x8*)&Bs[BUF][bOff + (NF) * 1024 + (GK)])

#define MF16(AV, BV, NLO) do {                                                         \
    __builtin_amdgcn_s_setprio(1);                                                     \
    _Pragma("unroll")                                                                  \
    for (int mf_ = 0; mf_ < 8; ++mf_) {                                                \
      acc[mf_][NLO]     = __builtin_amdgcn_mfma_f32_16x16x32_bf16(AV[mf_], BV[NLO],    \
                                                                  acc[mf_][NLO], 0, 0, 0); \
      acc[mf_][(NLO)+1] = __builtin_amdgcn_mfma_f32_16x16x32_bf16(AV[mf_], BV[(NLO)+1],\
                                                                  acc[mf_][(NLO)+1], 0, 0, 0); \
    }                                                                                  \
    __builtin_amdgcn_s_setprio(0);                                                     \
  } while (0)

#define BAR() __builtin_amdgcn_s_barrier()

  // prologue: tile0 (buf0) full + tile1 (buf1) h0 -> 12 loads in flight
  STG(0, 0, 0, 0); STG(1, 0, 0, 0); STG(0, 1, 0, 0); STG(1, 1, 0, 0);
  STG(0, 0, 1, 1); STG(1, 0, 1, 1);
  asm volatile("s_waitcnt vmcnt(4)" ::: "memory");   // tile0 landed; tile1-h0 in flight
  __builtin_amdgcn_s_barrier();

  for (int t = 0; t < T; ++t) {
    const int o = 2 * t + 1, n0 = 2 * t + 2, n1 = 2 * t + 3;
    bf16x8 a0[8], a1[8], b0[4], b1[4];
    // ---- even tile (buf0) ----
    // S1: reads buf0-gk0 | stage o-h1A -> buf1 (cross-buffer)
    #pragma unroll
    for (int i = 0; i < 8; ++i) a0[i] = LDA(0, gk0, i);
    #pragma unroll
    for (int i = 0; i < 4; ++i) b0[i] = LDB(0, gk0, i);
    STG(0, 1, o, 1);
    BAR();
    MF16(a0, b0, 0);
    // S2: reads buf0-gk1 (drain under S2 MFMA) | stage o-h1B -> buf1
    #pragma unroll
    for (int i = 0; i < 8; ++i) a1[i] = LDA(0, gk1, i);
    #pragma unroll
    for (int i = 0; i < 4; ++i) b1[i] = LDB(0, gk1, i);
    STG(1, 1, o, 1);
    BAR();
    __builtin_amdgcn_sched_barrier(0);   // pin: S3+ STG (buf0 write) stays below buf0 reads
    MF16(a0, b0, 2);
    // S3: stage n0-h0A -> buf0 (all buf0 reads completed in S1-S2)
    STG(0, 0, n0, 0);
    BAR();
    MF16(a1, b1, 0);
    // S4: stage n0-h0B -> buf0
    STG(1, 0, n0, 0);
    BAR();
    MF16(a1, b1, 2);
    // W1: odd tile fully landed (leaves n0-h0 in flight)
    if (t == T - 1) { asm volatile("s_waitcnt vmcnt(0)" ::: "memory"); }
    else            { asm volatile("s_waitcnt vmcnt(4)" ::: "memory"); }
    __builtin_amdgcn_s_barrier();
    // ---- odd tile (buf1) ----
    // S5: reads buf1-gk0 | stage n0-h1A -> buf0 (cross-buffer)
    #pragma unroll
    for (int i = 0; i < 8; ++i) a0[i] = LDA(1, gk0, i);
    #pragma unroll
    for (int i = 0; i < 4; ++i) b0[i] = LDB(1, gk0, i);
    STG(0, 1, n0, 0);
    BAR();
    MF16(a0, b0, 0);
    // S6: reads buf1-gk1 | stage n0-h1B -> buf0
    #pragma unroll
    for (int i = 0; i < 8; ++i) a1[i] = LDA(1, gk1, i);
    #pragma unroll
    for (int i = 0; i < 4; ++i) b1[i] = LDB(1, gk1, i);
    STG(1, 1, n0, 0);
    BAR();
    __builtin_amdgcn_sched_barrier(0);   // pin: S7+ STG (buf1 write) stays below buf1 reads
    MF16(a0, b0, 2);
    // S7: stage n1-h0A -> buf1 (all buf1 reads completed in S5-S6)
    STG(0, 0, n1, 1);
    BAR();
    MF16(a1, b1, 0);
    // S8: stage n1-h0B -> buf1
    STG(1, 0, n1, 1);
    BAR();
    MF16(a1, b1, 2);
    // W2: next even tile fully landed (leaves n1-h0 in flight)
    if (t < T - 1) {
      asm volatile("s_waitcnt vmcnt(4)" ::: "memory");
      __builtin_amdgcn_s_barrier();
    }
  }
#undef STG
#undef LDA
#undef LDB
#undef MF16
#undef BAR

  // epilogue: C/D layout col=lane&15, row=(lane>>4)*4+j  [m89-verified]
  unsigned short* Cb = (unsigned short*)C0 + (long)z * sCz;
  float* Cf = (float*)C0 + (long)z * sCz;
  const long crow0 = rowBase + wr * 128;
  const long ccol0 = colBase + wc * 64;
  #pragma unroll
  for (int mf = 0; mf < 8; ++mf) {
    #pragma unroll
    for (int j = 0; j < 4; ++j) {
      const long row = crow0 + mf * 16 + (lane >> 4) * 4 + j;
      const float brow = (BIAS_MODE == 2) ? bias[row] : 0.f;
      #pragma unroll
      for (int nf = 0; nf < 4; ++nf) {
        const long col = ccol0 + nf * 16 + (lane & 15);
        float v = acc[mf][nf][j] + brow;
        if (BIAS_MODE == 1) v += bias[col];
        if (OUT_BF16) Cb[row * 1024 + col] = f2bf(v);
        else          Cf[row * 1024 + col] = v;
      }
    }
  }
}

extern "C" void kernel_launch(void* const* d_in, const int* in_sizes, int n_in,
                              void* d_out, int out_size, void* d_ws, size_t ws_size,
                              hipStream_t stream) {
  (void)in_sizes; (void)n_in; (void)out_size; (void)ws_size;
  const float* Q   = (const float*)d_in[0];
  const float* src = (const float*)d_in[1];
  const float* Wq  = (const float*)d_in[2];
  const float* bq  = (const float*)d_in[3];
  const float* Wk  = (const float*)d_in[4];
  const float* bk  = (const float*)d_in[5];
  const float* Wv  = (const float*)d_in[6];
  const float* bv  = (const float*)d_in[7];
  const float* Wm1 = (const float*)d_in[8];
  const float* bm1 = (const float*)d_in[9];
  const float* Wm2 = (const float*)d_in[10];
  const float* bm2 = (const float*)d_in[11];
  const float* Wo  = (const float*)d_in[12];
  const float* bo  = (const float*)d_in[13];
  float* out = (float*)d_out;

  char* ws = (char*)d_ws;
  const long MBb = 1024L * 1024;  // bytes
  const long ME  = 1024L * 1024;  // elements per [1024][1024] slab
  // Region [0,64MB): staging buffers (dead before G4) then Sbuf (G4 logits),
  // then reused again as fp32 PV partials (G5) after softmax consumed Sbuf.
  unsigned short* Qbf   = (unsigned short*)(ws);             // 16 MB, dead after G1
  unsigned short* srcbf = (unsigned short*)(ws + 16 * MBb);  // 32 MB, dead after G3
  unsigned short* Wkbf  = (unsigned short*)(ws + 48 * MBb);  //  8 MB, dead after G2
  unsigned short* Wvbf  = (unsigned short*)(ws + 56 * MBb);  //  8 MB, dead after G3
  float*          Sbuf  = (float*)(ws);                      // 64 MB fp32 (G4 logits / G5 partials)
  unsigned short* Qpbf  = (unsigned short*)(ws + 64 * MBb);  // 16 MB
  unsigned short* Wqbf  = (unsigned short*)(ws + 80 * MBb);  //  2 MB
  unsigned short* Wobf  = (unsigned short*)(ws + 82 * MBb);  //  2 MB
  unsigned short* Kbf   = (unsigned short*)(ws + 84 * MBb);  // 32 MB
  unsigned short* Vtbf  = (unsigned short*)(ws + 116 * MBb); // 32 MB
  unsigned short* Pbf   = (unsigned short*)(ws + 148 * MBb); // 32 MB
  unsigned short* AObf  = (unsigned short*)(ws + 180 * MBb); // 16 MB
  float* Qmean  = (float*)(ws + 196 * MBb);
  float* pooled = (float*)(ws + 196 * MBb + 32 * 1024);
  float* hbuf   = (float*)(ws + 196 * MBb + 64 * 1024);
  int*   sel    = (int*)(ws + 196 * MBb + 96 * 1024);
  float* wsel   = (float*)(ws + 196 * MBb + 96 * 1024 + 256);

  // bf16 conversions of dense operands
  convert_bf16_kernel<<<4096, 256, 0, stream>>>(Q, Qbf);
  convert_bf16_kernel<<<512,  256, 0, stream>>>(Wq, Wqbf);
  convert_bf16_kernel<<<2048, 256, 0, stream>>>(Wk, Wkbf);
  convert_bf16_kernel<<<2048, 256, 0, stream>>>(Wv, Wvbf);
  convert_bf16_kernel<<<512,  256, 0, stream>>>(Wo, Wobf);

  // gate path, pure fp32 (exact top-k match with reference)
  zero_kernel<<<32, 256, 0, stream>>>(Qmean);
  qmean_kernel<<<dim3(4, 8, 16), 256, 0, stream>>>(Q, Qmean);
  matvec_kernel<0><<<2048, 256, 0, stream>>>(Qmean, Wq, bq, pooled);
  matvec_kernel<1><<<2048, 256, 0, stream>>>(pooled, Wm1, bm1, hbuf);
  gate_kernel<<<1, 256, 0, stream>>>(hbuf, Wm2, bm2, sel, wsel);

  // gather+convert only the top-2 selected src[p][b] slices
  select_convert_kernel<<<dim3(512, 16), 256, 0, stream>>>(src, sel, srcbf);

  // G1: Qp = Q·Wq^T + bq  -> bf16 [8192,1024]
  gemm256<1,1,0,0><<<128, 512, 0, stream>>>(Qbf, 0, Wqbf, 0, bq, 0, Qpbf, 0, nullptr, 1024);
  // G2: K[z] = src_sel[z]·Wk[p]^T + bk[p] -> bf16 [LK,D]
  gemm256<1,1,2,1><<<256, 512, 0, stream>>>(srcbf, ME, Wkbf, ME, bk, D_, Kbf, ME, sel, 1024);
  // G3: Vt[z] = Wv[p]·src_sel[z]^T + bv[p] (row-bias) -> bf16 [D,LK]
  gemm256<2,1,1,1><<<256, 512, 0, stream>>>(Wvbf, ME, srcbf, ME, bv, D_, Vtbf, ME, sel, 1024);
  // G4: S[z] = Qp[b]·K[z]^T -> fp32 logits (scale folded into softmax)
  gemm256<0,0,3,1><<<256, 512, 0, stream>>>(Qpbf, ME, Kbf, ME, nullptr, 0, Sbuf, ME, nullptr, 1024);
  // softmax rows, fold 1/32 scale and gate weight, emit bf16 P
  softmax_kernel<<<dim3(256, 16), 256, 0, stream>>>(Sbuf, Pbf, wsel);
  // G5: partial[z] = P[z]·Vt[z]^T -> fp32 (full 256-block grid; K=1024 each)
  gemm256<0,0,0,1><<<256, 512, 0, stream>>>(Pbf, ME, Vtbf, ME, nullptr, 0, Sbuf, ME, nullptr, 1024);
  // combine slot pairs -> bf16 AO
  combine_kernel<<<dim3(1024, 8), 256, 0, stream>>>(Sbuf, AObf);
  // G6: out = AO·Wo^T + bo -> fp32 output
  gemm256<1,0,0,0><<<128, 512, 0, stream>>>(AObf, 0, Wobf, 0, bo, 0, out, 0, nullptr, 1024);
}